// Round 13
// baseline (338.464 us; speedup 1.0000x reference)
//
#include <hip/hip_runtime.h>
#include <cstdint>
#include <cstddef>

typedef unsigned short u16;
typedef unsigned int u32;
typedef __attribute__((ext_vector_type(2))) unsigned short u16x2;
typedef __attribute__((ext_vector_type(4))) unsigned short u16x4;
typedef __attribute__((ext_vector_type(8))) unsigned short u16x8;
typedef __attribute__((ext_vector_type(8))) __bf16 bf16x8;
typedef __attribute__((ext_vector_type(4))) float f32x4;

__device__ __forceinline__ float wred(float v) {
#pragma unroll
  for (int m = 32; m >= 1; m >>= 1) v += __shfl_xor(v, m, 64);
  return v;
}
__device__ __forceinline__ u16 f2bf(float f) {
  u32 u = __float_as_uint(f);
  u += 0x7fffu + ((u >> 16) & 1u);
  return (u16)(u >> 16);
}
__device__ __forceinline__ float bflo(u32 u) { return __uint_as_float(u << 16); }
__device__ __forceinline__ float bfhi(u32 u) { return __uint_as_float(u & 0xffff0000u); }
__device__ __forceinline__ u32 pack2(float a, float b) {
  u32 ua = __float_as_uint(a); ua += 0x7fffu + ((ua >> 16) & 1u);
  u32 ub = __float_as_uint(b); ub += 0x7fffu + ((ub >> 16) & 1u);
  return (ua >> 16) | (ub & 0xffff0000u);
}

// 32x128 @ 128x128 MFMA from xs tile (uses m0, ntb, lane, xs from scope)
#define MFMA128_FROM_XS(ACC, BP)                                               \
  {                                                                            \
    const int ar_ = m0 + (lane & 15);                                          \
    const int akb_ = (lane >> 4) << 2;                                         \
    _Pragma("unroll")                                                          \
    for (int kc = 0; kc < 4; ++kc) {                                           \
      u16x4 lo = *(const u16x4*)&xs[ar_][kc * 32 + akb_];                      \
      u16x4 hi = *(const u16x4*)&xs[ar_][kc * 32 + akb_ + 16];                 \
      u16x8 av;                                                                \
      _Pragma("unroll")                                                        \
      for (int j = 0; j < 4; ++j) { av[j] = lo[j]; av[j + 4] = hi[j]; }        \
      bf16x8 a = __builtin_bit_cast(bf16x8, av);                               \
      _Pragma("unroll")                                                        \
      for (int t = 0; t < 4; ++t) {                                            \
        bf16x8 b = (BP)[(kc * 8 + ntb + t) * 64 + lane];                       \
        (ACC)[t] = __builtin_amdgcn_mfma_f32_16x16x32_bf16(a, b, (ACC)[t], 0, 0, 0); \
      }                                                                        \
    }                                                                          \
  }

// D1: blocks [0,nb): scan_block over degree (+ inv); [nb,nb+60): weight pack
__global__ __launch_bounds__(256) void d1_scan_pack_k(
    const float* __restrict__ deg, int* __restrict__ offs,
    int* __restrict__ bsum, float* __restrict__ inv, int N, int nb,
    const float* __restrict__ Win, const float* __restrict__ W1,
    const float* __restrict__ W2, const float* __restrict__ Wout,
    u16* __restrict__ pWin, u16* __restrict__ pW1,
    u16* __restrict__ pW2, u16* __restrict__ pWout) {
  if ((int)blockIdx.x < nb) {
    __shared__ int sh[256];
    int tid = threadIdx.x;
    int i = blockIdx.x * 256 + tid;
    int c = (i < N) ? (int)(deg[i] + 0.5f) : 0;
    if (i < N) inv[i] = rsqrtf(deg[i] + 1.0f);
    int val = c;
    for (int off = 1; off < 256; off <<= 1) {
      sh[tid] = val; __syncthreads();
      if (tid >= off) val += sh[tid - off];
      __syncthreads();
    }
    if (i < N) offs[i] = val - c;
    if (tid == 255) bsum[blockIdx.x] = val;
    return;
  }
  const int b = blockIdx.x - nb;
  const float* W; u16* P; int ncol; int t;
  if (b < 8)       { W = Win;                        P = pWin;                      ncol = 128; t = b * 256 + threadIdx.x; }
  else if (b < 32) { int l = (b - 8) / 8;  W = W1 + (size_t)l * 16384;  P = pW1 + (size_t)l * 16384; ncol = 128; t = ((b - 8) % 8) * 256 + threadIdx.x; }
  else if (b < 56) { int l = (b - 32) / 8; W = W2 + (size_t)l * 16384;  P = pW2 + (size_t)l * 16384; ncol = 128; t = ((b - 32) % 8) * 256 + threadIdx.x; }
  else             { W = Wout;                       P = pWout;                     ncol = 64;  t = (b - 56) * 256 + threadIdx.x; }
  int NT = ncol >> 4;
  int total = 4 * NT * 64;
  if (t >= total) return;
  int lane = t & 63;
  int tmp = t >> 6;
  int nt = tmp % NT, kc = tmp / NT;
  int n = nt * 16 + (lane & 15);
  int kb = kc * 32 + ((lane >> 4) << 2);
  u16* dst = P + (size_t)t * 8;
#pragma unroll
  for (int j = 0; j < 8; ++j) {
    int k = kb + (j & 3) + ((j >> 2) << 4);
    dst[j] = f2bf(W[(size_t)k * ncol + n]);
  }
}

// D2: blocks [0,gemmGrid): fused x@Win+ReLU -> h, then y@W1 -> msc
//     last block: exclusive-scan of bsum (nb <= 512) + gcur zero-init
__global__ __launch_bounds__(256) void in_scale_k(
    const float* __restrict__ x, const u16* __restrict__ pWin,
    const float* __restrict__ b_in, const u16* __restrict__ pW1,
    const float* __restrict__ b1, const float* __restrict__ inv,
    u32* __restrict__ h, u16* __restrict__ msc, int N,
    int* __restrict__ bsum, int nb, int* __restrict__ gcur) {
  if (blockIdx.x == gridDim.x - 1) {
    __shared__ int a_[512], b_[512];
    int tid = threadIdx.x;
    gcur[tid] = 0;
    for (int i = tid; i < 512; i += 256) a_[i] = (i < nb) ? bsum[i] : 0;
    __syncthreads();
    int* src = a_; int* dst = b_;
    for (int off = 1; off < 512; off <<= 1) {
      for (int i = tid; i < 512; i += 256)
        dst[i] = (i >= off) ? src[i] + src[i - off] : src[i];
      __syncthreads();
      int* t = src; src = dst; dst = t;
    }
    for (int i = tid; i < nb; i += 256) bsum[i] = (i > 0) ? src[i - 1] : 0;
    return;
  }
  __shared__ u16 xs[32][136];
  __shared__ float cs[16][132];
  const int tid = threadIdx.x;
  const int lane = tid & 63, wid = tid >> 6;
  const int row0 = blockIdx.x * 32;

  for (int i = tid; i < 1024; i += 256) {
    int r = i >> 5, c4 = i & 31;
    float4 v = ((const float4*)(x + (size_t)(row0 + r) * 128))[c4];
    u16x4 o = {f2bf(v.x), f2bf(v.y), f2bf(v.z), f2bf(v.w)};
    *(u16x4*)&xs[r][c4 * 4] = o;
  }
  __syncthreads();

  const int m0  = (wid >> 1) << 4;
  const int ntb = (wid & 1) << 2;
  f32x4 acc[4];
#pragma unroll
  for (int t = 0; t < 4; ++t) acc[t] = (f32x4){0.f, 0.f, 0.f, 0.f};
  MFMA128_FROM_XS(acc, (const bf16x8*)pWin);

  const int cb = lane & 15;
  const int rg = (lane >> 4) << 2;
#pragma unroll
  for (int hh = 0; hh < 2; ++hh) {
    __syncthreads();
    if ((m0 >> 4) == hh) {
#pragma unroll
      for (int t = 0; t < 4; ++t) {
        int colm = (ntb + t) * 16 + cb;
        float bv = b_in[colm];
#pragma unroll
        for (int r = 0; r < 4; ++r) cs[rg + r][colm] = acc[t][r] + bv;
      }
    }
    __syncthreads();
    for (int rr = 0; rr < 4; ++rr) {
      int lr = wid * 4 + rr;
      int r = hh * 16 + lr;
      int gr = row0 + r;
      float2 t2 = *(const float2*)&cs[lr][lane * 2];
      u32 pk = pack2(fmaxf(t2.x, 0.f), fmaxf(t2.y, 0.f));
      h[(size_t)gr * 64 + lane] = pk;
      *(u32*)&xs[r][lane * 2] = pk;
    }
  }
  __syncthreads();

  f32x4 acc2[4];
#pragma unroll
  for (int t = 0; t < 4; ++t) acc2[t] = (f32x4){0.f, 0.f, 0.f, 0.f};
  MFMA128_FROM_XS(acc2, (const bf16x8*)pW1);
  float iv4[4];
#pragma unroll
  for (int r = 0; r < 4; ++r) iv4[r] = inv[row0 + m0 + rg + r];
#pragma unroll
  for (int t = 0; t < 4; ++t) {
    int colm = (ntb + t) * 16 + cb;
    float bv = b1[colm];
#pragma unroll
    for (int r = 0; r < 4; ++r) {
      int gr = row0 + m0 + rg + r;
      msc[(size_t)gr * 128 + colm] = f2bf((acc2[t][r] + bv) * iv4[r]);
    }
  }
}

// D3: bucket-scatter edges into packed u32 (src | dstoff<<17).
// Bucket base derived from raw offs + scanned bsum; gcur is a relative cursor.
__global__ __launch_bounds__(256) void scatter_k(
    const int* __restrict__ src, const int* __restrict__ dst,
    int* __restrict__ gcur, u32* __restrict__ pairs,
    const int* __restrict__ offs, const int* __restrict__ bsum, int E) {
  __shared__ int hist[256];
  __shared__ int base_[256];
  const int tid = threadIdx.x;
  const int e0 = blockIdx.x * 8192;
  const int e1 = min(E, e0 + 8192);
  hist[tid] = 0;
  __syncthreads();
  for (int e = e0 + tid; e < e1; e += 256)
    atomicAdd(&hist[dst[e] >> 9], 1);
  __syncthreads();
  int c = hist[tid];
  if (c > 0) {
    int n0 = tid << 9;
    int bucket_base = offs[n0] + bsum[n0 >> 8];
    base_[tid] = bucket_base + atomicAdd(&gcur[tid], c);
  }
  hist[tid] = 0;
  __syncthreads();
  for (int e = e0 + tid; e < e1; e += 256) {
    int d = dst[e];
    int b = d >> 9;
    int r = atomicAdd(&hist[b], 1);
    pairs[base_[b] + r] = (u32)src[e] | ((u32)(d & 511) << 17);
  }
}

// D4: blocks [0,NB): per-bucket CSR fill (cursors finalized locally);
//     blocks [NB,NB+saGrid): write finalized offs2.
__global__ __launch_bounds__(256) void fill2_k(
    const u32* __restrict__ pairs, const int* __restrict__ offs,
    const int* __restrict__ bsum, int* __restrict__ col,
    int* __restrict__ offs2, int N, int E, int NB) {
  const int tid = threadIdx.x;
  if ((int)blockIdx.x >= NB) {
    int i = (blockIdx.x - NB) * 256 + tid;
    if (i < N) offs2[i] = offs[i] + bsum[i >> 8];
    else if (i == N) offs2[N] = E;
    return;
  }
  __shared__ int cur[512];
  const int b = blockIdx.x;
  const int n0 = b << 9;
  const int n1 = min(N, n0 + 512);
  for (int i = tid; i < n1 - n0; i += 256)
    cur[i] = offs[n0 + i] + bsum[(n0 + i) >> 8];
  __syncthreads();
  const int e0 = offs[n0] + bsum[n0 >> 8];
  const int e1 = (n1 == N) ? E : offs[n1] + bsum[n1 >> 8];
  for (int e = e0 + tid; e < e1; e += 256) {
    u32 pr = pairs[e];
    int p = atomicAdd(&cur[pr >> 17], 1);
    col[p] = (int)(pr & 0x1FFFFu);
  }
}

// D5..D7: fused layer = SpMM gather + W2 GEMM + res/LN/ReLU + next GEMM.
// FINAL==0: write h; phase3 = y @ W1next -> msc_out (inv-scaled).
// FINAL==1: no h write; out-LN in-register; phase3 = z @ Wout -> d_out (fp32).
template <int FINAL>
__global__ __launch_bounds__(256, 6) void layer_fused_k(
    const uint4* __restrict__ mscin, const int* __restrict__ offs,
    const int* __restrict__ col, const float* __restrict__ inv,
    const u16* __restrict__ pW2, const float* __restrict__ b2,
    u32* __restrict__ h, const float* __restrict__ g1,
    const float* __restrict__ lb1,
    const u16* __restrict__ pWn, const float* __restrict__ bn,
    void* __restrict__ outv, const float* __restrict__ og,
    const float* __restrict__ ob, int N) {
  __shared__ u16 xs[32][136];
  __shared__ float cs[16][132];
  const int tid = threadIdx.x;
  const int lane = tid & 63, wid = tid >> 6;
  const int row0 = blockIdx.x * 32;
  const int rgrp = lane >> 4, c = lane & 15;

  // ---- phase 1: gather (reduce-free, MLP 8) ----
#pragma unroll
  for (int p = 0; p < 2; ++p) {
    const int lrow = wid * 8 + p * 4 + rgrp;
    const int d = row0 + lrow;
    const int s0 = offs[d], s1 = offs[d + 1];
    const int last = s1 - 1;
    float2 a0 = {0.f, 0.f}, a1 = {0.f, 0.f}, a2 = {0.f, 0.f}, a3 = {0.f, 0.f};
    for (int k = s0; k < s1; k += 8) {
      int sv[8];
#pragma unroll
      for (int j = 0; j < 8; ++j) sv[j] = col[min(k + j, last)];
      uint4 rv[8];
#pragma unroll
      for (int j = 0; j < 8; ++j) rv[j] = mscin[(size_t)sv[j] * 16 + c];
#pragma unroll
      for (int j = 0; j < 8; ++j) {
        float m = (k + j < s1) ? 1.f : 0.f;
        a0.x = fmaf(m, bflo(rv[j].x), a0.x); a0.y = fmaf(m, bfhi(rv[j].x), a0.y);
        a1.x = fmaf(m, bflo(rv[j].y), a1.x); a1.y = fmaf(m, bfhi(rv[j].y), a1.y);
        a2.x = fmaf(m, bflo(rv[j].z), a2.x); a2.y = fmaf(m, bfhi(rv[j].z), a2.y);
        a3.x = fmaf(m, bflo(rv[j].w), a3.x); a3.y = fmaf(m, bfhi(rv[j].w), a3.y);
      }
    }
    uint4 r = mscin[(size_t)d * 16 + c];   // self loop
    float iv = inv[d];
    uint4 o;
    o.x = pack2((a0.x + bflo(r.x)) * iv, (a0.y + bfhi(r.x)) * iv);
    o.y = pack2((a1.x + bflo(r.y)) * iv, (a1.y + bfhi(r.y)) * iv);
    o.z = pack2((a2.x + bflo(r.z)) * iv, (a2.y + bfhi(r.z)) * iv);
    o.w = pack2((a3.x + bflo(r.w)) * iv, (a3.y + bfhi(r.w)) * iv);
    *(uint4*)&xs[lrow][c * 8] = o;
  }
  __syncthreads();

  // ---- phase 2: W2 MFMA ----
  const int m0  = (wid >> 1) << 4;
  const int ntb = (wid & 1) << 2;
  f32x4 acc[4];
#pragma unroll
  for (int t = 0; t < 4; ++t) acc[t] = (f32x4){0.f, 0.f, 0.f, 0.f};
  MFMA128_FROM_XS(acc, (const bf16x8*)pW2);

  // ---- epilogue: bias + residual + LN + ReLU (y -> h and/or xs) ----
  const int cb = lane & 15;
  const int rg = (lane >> 4) << 2;
  float2 gg = *(const float2*)&g1[lane * 2];
  float2 bb = *(const float2*)&lb1[lane * 2];
  float2 ogg, obb;
  if constexpr (FINAL) {
    ogg = *(const float2*)&og[lane * 2];
    obb = *(const float2*)&ob[lane * 2];
  }
#pragma unroll
  for (int hh = 0; hh < 2; ++hh) {
    __syncthreads();
    if ((m0 >> 4) == hh) {
#pragma unroll
      for (int t = 0; t < 4; ++t) {
        int colm = (ntb + t) * 16 + cb;
        float bv = b2[colm];
#pragma unroll
        for (int r = 0; r < 4; ++r) cs[rg + r][colm] = acc[t][r] + bv;
      }
    }
    __syncthreads();
    for (int rr = 0; rr < 4; ++rr) {
      int lr = wid * 4 + rr;
      int r = hh * 16 + lr;
      int gr = row0 + r;
      float2 t2 = *(const float2*)&cs[lr][lane * 2];
      u32 hv = h[(size_t)gr * 64 + lane];
      float tx = t2.x + bflo(hv), ty = t2.y + bfhi(hv);
      float mean = wred(tx + ty) * (1.f / 128.f);
      float dx = tx - mean, dy = ty - mean;
      float var = wred(dx * dx + dy * dy) * (1.f / 128.f);
      float rstd = rsqrtf(var + 1e-5f);
      float y0 = fmaxf(dx * rstd * gg.x + bb.x, 0.f);
      float y1 = fmaxf(dy * rstd * gg.y + bb.y, 0.f);
      if constexpr (!FINAL) {
        u32 pk = pack2(y0, y1);
        h[(size_t)gr * 64 + lane] = pk;
        *(u32*)&xs[r][lane * 2] = pk;
      } else {
        float m2 = wred(y0 + y1) * (1.f / 128.f);
        float dx2 = y0 - m2, dy2 = y1 - m2;
        float v2 = wred(dx2 * dx2 + dy2 * dy2) * (1.f / 128.f);
        float rs2 = rsqrtf(v2 + 1e-5f);
        *(u32*)&xs[r][lane * 2] =
            pack2(dx2 * rs2 * ogg.x + obb.x, dy2 * rs2 * ogg.y + obb.y);
      }
    }
  }
  __syncthreads();

  // ---- phase 3 ----
  if constexpr (!FINAL) {
    f32x4 acc2[4];
#pragma unroll
    for (int t = 0; t < 4; ++t) acc2[t] = (f32x4){0.f, 0.f, 0.f, 0.f};
    MFMA128_FROM_XS(acc2, (const bf16x8*)pWn);
    u16* Y = (u16*)outv;
    float iv4[4];
#pragma unroll
    for (int r = 0; r < 4; ++r) iv4[r] = inv[row0 + m0 + rg + r];
#pragma unroll
    for (int t = 0; t < 4; ++t) {
      int colm = (ntb + t) * 16 + cb;
      float bv = bn[colm];
#pragma unroll
      for (int r = 0; r < 4; ++r) {
        int gr = row0 + m0 + rg + r;
        Y[(size_t)gr * 128 + colm] = f2bf((acc2[t][r] + bv) * iv4[r]);
      }
    }
  } else {
    const int m0b = (wid & 1) << 4;
    const int ntbb = (wid >> 1) << 1;
    const int arb = m0b + (lane & 15);
    const int akb = (lane >> 4) << 2;
    f32x4 acc2[2];
#pragma unroll
    for (int t = 0; t < 2; ++t) acc2[t] = (f32x4){0.f, 0.f, 0.f, 0.f};
    const bf16x8* Bp = (const bf16x8*)pWn;
#pragma unroll
    for (int kc = 0; kc < 4; ++kc) {
      u16x4 lo = *(const u16x4*)&xs[arb][kc * 32 + akb];
      u16x4 hi = *(const u16x4*)&xs[arb][kc * 32 + akb + 16];
      u16x8 av;
#pragma unroll
      for (int j = 0; j < 4; ++j) { av[j] = lo[j]; av[j + 4] = hi[j]; }
      bf16x8 a = __builtin_bit_cast(bf16x8, av);
#pragma unroll
      for (int t = 0; t < 2; ++t) {
        bf16x8 b = Bp[(kc * 4 + ntbb + t) * 64 + lane];
        acc2[t] = __builtin_amdgcn_mfma_f32_16x16x32_bf16(a, b, acc2[t], 0, 0, 0);
      }
    }
    float* Y = (float*)outv;
#pragma unroll
    for (int t = 0; t < 2; ++t) {
      int colo = (ntbb + t) * 16 + cb;
      float bv = bn[colo];
#pragma unroll
      for (int r = 0; r < 4; ++r) {
        int gr = row0 + m0b + rg + r;
        Y[(size_t)gr * 64 + colo] = acc2[t][r] + bv;
      }
    }
  }
}

// ---------------------------------------------------------------------------
extern "C" void kernel_launch(void* const* d_in, const int* in_sizes, int n_in,
                              void* d_out, int out_size, void* d_ws, size_t ws_size,
                              hipStream_t stream) {
  (void)n_in; (void)out_size; (void)ws_size;
  const float* x      = (const float*)d_in[0];
  const int*   eidx   = (const int*)d_in[1];
  const float* degree = (const float*)d_in[2];
  const float* Win    = (const float*)d_in[3];
  const float* b_in   = (const float*)d_in[4];
  const float* W1     = (const float*)d_in[5];
  const float* b1     = (const float*)d_in[6];
  const float* W2     = (const float*)d_in[7];
  const float* b2     = (const float*)d_in[8];
  const float* ln_g   = (const float*)d_in[9];
  const float* ln_b   = (const float*)d_in[10];
  const float* out_g  = (const float*)d_in[11];
  const float* out_b  = (const float*)d_in[12];
  const float* Wout   = (const float*)d_in[13];
  const float* b_out  = (const float*)d_in[14];

  const int N = in_sizes[0] / 128;
  const int E = in_sizes[1] / 2;
  const int* esrc = eidx;
  const int* edst = eidx + E;

  char* p = (char*)d_ws;
  auto alloc = [&](size_t bytes) {
    char* q = p;
    p += (bytes + 255) & ~(size_t)255;
    return q;
  };
  float* inv    = (float*)alloc((size_t)N * 4);
  int*   offs   = (int*)alloc(((size_t)N + 1) * 4);
  int*   offs2  = (int*)alloc(((size_t)N + 1) * 4);
  int*   gcur   = (int*)alloc(256 * 4);
  int*   bsum   = (int*)alloc(1024 * 4);
  int*   col    = (int*)alloc((size_t)E * 4);
  u32*   pairs  = (u32*)alloc((size_t)E * 4);
  u32*   h      = (u32*)alloc((size_t)N * 128 * 2);     // bf16 residual
  u32*   mscA   = (u32*)alloc((size_t)N * 128 * 2);     // bf16 ping
  u32*   mscB   = (u32*)alloc((size_t)N * 128 * 2);     // bf16 pong
  u16*   pWin   = (u16*)alloc(4 * 8 * 64 * 8 * 2);
  u16*   pWout  = (u16*)alloc(4 * 4 * 64 * 8 * 2);
  u16*   pW1    = (u16*)alloc(3 * 4 * 8 * 64 * 8 * 2);
  u16*   pW2    = (u16*)alloc(3 * 4 * 8 * 64 * 8 * 2);

  const int nb = (N + 255) / 256;              // scan blocks (<=512 req'd)
  const int NB = (N + 511) / 512;              // dst buckets
  const int gemmGrid = (N + 31) / 32;          // 3125
  const int saGrid = (N + 256) / 256;

  // D1: degree scan + inv + weight packing
  d1_scan_pack_k<<<nb + 60, 256, 0, stream>>>(
      degree, offs, bsum, inv, N, nb,
      Win, W1, W2, Wout, pWin, pW1, pW2, pWout);
  // D2: x@Win+ReLU -> h, y@W1(l0) -> mscA  (+ bsum scan, gcur init)
  in_scale_k<<<gemmGrid + 1, 256, 0, stream>>>(
      x, pWin, b_in, pW1, b1, inv, h, (u16*)mscA, N, bsum, nb, gcur);
  // D3: edge bucket-scatter (derives bucket bases from offs+bsum)
  scatter_k<<<(E + 8191) / 8192, 256, 0, stream>>>(
      esrc, edst, gcur, pairs, offs, bsum, E);
  // D4: CSR fill + offs2 finalize
  fill2_k<<<NB + saGrid, 256, 0, stream>>>(
      pairs, offs, bsum, col, offs2, N, E, NB);

  // D5: layer 0  (mscA -> h, mscB)
  layer_fused_k<0><<<gemmGrid, 256, 0, stream>>>(
      (const uint4*)mscA, offs2, col, inv, pW2, b2, h, ln_g, ln_b,
      pW1 + 16384, b1 + 128, mscB, nullptr, nullptr, N);
  // D6: layer 1  (mscB -> h, mscA)
  layer_fused_k<0><<<gemmGrid, 256, 0, stream>>>(
      (const uint4*)mscB, offs2, col, inv, pW2 + 16384, b2 + 128, h,
      ln_g + 128, ln_b + 128, pW1 + 32768, b1 + 256, mscA, nullptr, nullptr, N);
  // D7: layer 2 + out-LN + Wout  (mscA -> d_out)
  layer_fused_k<1><<<gemmGrid, 256, 0, stream>>>(
      (const uint4*)mscA, offs2, col, inv, pW2 + 32768, b2 + 256, h,
      ln_g + 256, ln_b + 256, pWout, b_out, d_out, out_g, out_b, N);
}

// Round 14
// 331.131 us; speedup vs baseline: 1.0221x; 1.0221x over previous
//
#include <hip/hip_runtime.h>
#include <cstdint>
#include <cstddef>

typedef unsigned short u16;
typedef unsigned int u32;
typedef __attribute__((ext_vector_type(2))) unsigned short u16x2;
typedef __attribute__((ext_vector_type(4))) unsigned short u16x4;
typedef __attribute__((ext_vector_type(8))) unsigned short u16x8;
typedef __attribute__((ext_vector_type(8))) __bf16 bf16x8;
typedef __attribute__((ext_vector_type(4))) float f32x4;

__device__ __forceinline__ float wred(float v) {
#pragma unroll
  for (int m = 32; m >= 1; m >>= 1) v += __shfl_xor(v, m, 64);
  return v;
}
__device__ __forceinline__ u16 f2bf(float f) {
  u32 u = __float_as_uint(f);
  u += 0x7fffu + ((u >> 16) & 1u);
  return (u16)(u >> 16);
}
__device__ __forceinline__ float bflo(u32 u) { return __uint_as_float(u << 16); }
__device__ __forceinline__ float bfhi(u32 u) { return __uint_as_float(u & 0xffff0000u); }
__device__ __forceinline__ u32 pack2(float a, float b) {
  u32 ua = __float_as_uint(a); ua += 0x7fffu + ((ua >> 16) & 1u);
  u32 ub = __float_as_uint(b); ub += 0x7fffu + ((ub >> 16) & 1u);
  return (ua >> 16) | (ub & 0xffff0000u);
}

// 32x128 @ 128x128 MFMA from xs tile (uses m0, ntb, lane, xs from scope)
#define MFMA128_FROM_XS(ACC, BP)                                               \
  {                                                                            \
    const int ar_ = m0 + (lane & 15);                                          \
    const int akb_ = (lane >> 4) << 2;                                         \
    _Pragma("unroll")                                                          \
    for (int kc = 0; kc < 4; ++kc) {                                           \
      u16x4 lo = *(const u16x4*)&xs[ar_][kc * 32 + akb_];                      \
      u16x4 hi = *(const u16x4*)&xs[ar_][kc * 32 + akb_ + 16];                 \
      u16x8 av;                                                                \
      _Pragma("unroll")                                                        \
      for (int j = 0; j < 4; ++j) { av[j] = lo[j]; av[j + 4] = hi[j]; }        \
      bf16x8 a = __builtin_bit_cast(bf16x8, av);                               \
      _Pragma("unroll")                                                        \
      for (int t = 0; t < 4; ++t) {                                            \
        bf16x8 b = (BP)[(kc * 8 + ntb + t) * 64 + lane];                       \
        (ACC)[t] = __builtin_amdgcn_mfma_f32_16x16x32_bf16(a, b, (ACC)[t], 0, 0, 0); \
      }                                                                        \
    }                                                                          \
  }

// D1: blocks [0,nb): scan_block over degree (+ inv); [nb,nb+60): weight pack
__global__ __launch_bounds__(256) void d1_scan_pack_k(
    const float* __restrict__ deg, int* __restrict__ offs,
    int* __restrict__ bsum, float* __restrict__ inv, int N, int nb,
    const float* __restrict__ Win, const float* __restrict__ W1,
    const float* __restrict__ W2, const float* __restrict__ Wout,
    u16* __restrict__ pWin, u16* __restrict__ pW1,
    u16* __restrict__ pW2, u16* __restrict__ pWout) {
  if ((int)blockIdx.x < nb) {
    __shared__ int sh[256];
    int tid = threadIdx.x;
    int i = blockIdx.x * 256 + tid;
    int c = (i < N) ? (int)(deg[i] + 0.5f) : 0;
    if (i < N) inv[i] = rsqrtf(deg[i] + 1.0f);
    int val = c;
    for (int off = 1; off < 256; off <<= 1) {
      sh[tid] = val; __syncthreads();
      if (tid >= off) val += sh[tid - off];
      __syncthreads();
    }
    if (i < N) offs[i] = val - c;
    if (tid == 255) bsum[blockIdx.x] = val;
    return;
  }
  const int b = blockIdx.x - nb;
  const float* W; u16* P; int ncol; int t;
  if (b < 8)       { W = Win;                        P = pWin;                      ncol = 128; t = b * 256 + threadIdx.x; }
  else if (b < 32) { int l = (b - 8) / 8;  W = W1 + (size_t)l * 16384;  P = pW1 + (size_t)l * 16384; ncol = 128; t = ((b - 8) % 8) * 256 + threadIdx.x; }
  else if (b < 56) { int l = (b - 32) / 8; W = W2 + (size_t)l * 16384;  P = pW2 + (size_t)l * 16384; ncol = 128; t = ((b - 32) % 8) * 256 + threadIdx.x; }
  else             { W = Wout;                       P = pWout;                     ncol = 64;  t = (b - 56) * 256 + threadIdx.x; }
  int NT = ncol >> 4;
  int total = 4 * NT * 64;
  if (t >= total) return;
  int lane = t & 63;
  int tmp = t >> 6;
  int nt = tmp % NT, kc = tmp / NT;
  int n = nt * 16 + (lane & 15);
  int kb = kc * 32 + ((lane >> 4) << 2);
  u16* dst = P + (size_t)t * 8;
#pragma unroll
  for (int j = 0; j < 8; ++j) {
    int k = kb + (j & 3) + ((j >> 2) << 4);
    dst[j] = f2bf(W[(size_t)k * ncol + n]);
  }
}

// D2: blocks [0,gemmGrid): fused x@Win+ReLU -> h, then y@W1 -> msc
//     last block: exclusive-scan of bsum (nb <= 512) + gcur zero-init
__global__ __launch_bounds__(256) void in_scale_k(
    const float* __restrict__ x, const u16* __restrict__ pWin,
    const float* __restrict__ b_in, const u16* __restrict__ pW1,
    const float* __restrict__ b1, const float* __restrict__ inv,
    u32* __restrict__ h, u16* __restrict__ msc, int N,
    int* __restrict__ bsum, int nb, int* __restrict__ gcur) {
  if (blockIdx.x == gridDim.x - 1) {
    __shared__ int a_[512], b_[512];
    int tid = threadIdx.x;
    gcur[tid] = 0;
    for (int i = tid; i < 512; i += 256) a_[i] = (i < nb) ? bsum[i] : 0;
    __syncthreads();
    int* src = a_; int* dst = b_;
    for (int off = 1; off < 512; off <<= 1) {
      for (int i = tid; i < 512; i += 256)
        dst[i] = (i >= off) ? src[i] + src[i - off] : src[i];
      __syncthreads();
      int* t = src; src = dst; dst = t;
    }
    for (int i = tid; i < nb; i += 256) bsum[i] = (i > 0) ? src[i - 1] : 0;
    return;
  }
  __shared__ u16 xs[32][136];
  __shared__ float cs[16][132];
  const int tid = threadIdx.x;
  const int lane = tid & 63, wid = tid >> 6;
  const int row0 = blockIdx.x * 32;

  for (int i = tid; i < 1024; i += 256) {
    int r = i >> 5, c4 = i & 31;
    float4 v = ((const float4*)(x + (size_t)(row0 + r) * 128))[c4];
    u16x4 o = {f2bf(v.x), f2bf(v.y), f2bf(v.z), f2bf(v.w)};
    *(u16x4*)&xs[r][c4 * 4] = o;
  }
  __syncthreads();

  const int m0  = (wid >> 1) << 4;
  const int ntb = (wid & 1) << 2;
  f32x4 acc[4];
#pragma unroll
  for (int t = 0; t < 4; ++t) acc[t] = (f32x4){0.f, 0.f, 0.f, 0.f};
  MFMA128_FROM_XS(acc, (const bf16x8*)pWin);

  const int cb = lane & 15;
  const int rg = (lane >> 4) << 2;
#pragma unroll
  for (int hh = 0; hh < 2; ++hh) {
    __syncthreads();
    if ((m0 >> 4) == hh) {
#pragma unroll
      for (int t = 0; t < 4; ++t) {
        int colm = (ntb + t) * 16 + cb;
        float bv = b_in[colm];
#pragma unroll
        for (int r = 0; r < 4; ++r) cs[rg + r][colm] = acc[t][r] + bv;
      }
    }
    __syncthreads();
    for (int rr = 0; rr < 4; ++rr) {
      int lr = wid * 4 + rr;
      int r = hh * 16 + lr;
      int gr = row0 + r;
      float2 t2 = *(const float2*)&cs[lr][lane * 2];
      u32 pk = pack2(fmaxf(t2.x, 0.f), fmaxf(t2.y, 0.f));
      h[(size_t)gr * 64 + lane] = pk;
      *(u32*)&xs[r][lane * 2] = pk;
    }
  }
  __syncthreads();

  f32x4 acc2[4];
#pragma unroll
  for (int t = 0; t < 4; ++t) acc2[t] = (f32x4){0.f, 0.f, 0.f, 0.f};
  MFMA128_FROM_XS(acc2, (const bf16x8*)pW1);
  float iv4[4];
#pragma unroll
  for (int r = 0; r < 4; ++r) iv4[r] = inv[row0 + m0 + rg + r];
#pragma unroll
  for (int t = 0; t < 4; ++t) {
    int colm = (ntb + t) * 16 + cb;
    float bv = b1[colm];
#pragma unroll
    for (int r = 0; r < 4; ++r) {
      int gr = row0 + m0 + rg + r;
      msc[(size_t)gr * 128 + colm] = f2bf((acc2[t][r] + bv) * iv4[r]);
    }
  }
}

// D3: bucket-scatter edges into packed u32 (src | dstoff<<17).
// Bucket base derived from raw offs + scanned bsum; gcur is a relative cursor.
__global__ __launch_bounds__(256) void scatter_k(
    const int* __restrict__ src, const int* __restrict__ dst,
    int* __restrict__ gcur, u32* __restrict__ pairs,
    const int* __restrict__ offs, const int* __restrict__ bsum, int E) {
  __shared__ int hist[256];
  __shared__ int base_[256];
  const int tid = threadIdx.x;
  const int e0 = blockIdx.x * 8192;
  const int e1 = min(E, e0 + 8192);
  hist[tid] = 0;
  __syncthreads();
  for (int e = e0 + tid; e < e1; e += 256)
    atomicAdd(&hist[dst[e] >> 9], 1);
  __syncthreads();
  int c = hist[tid];
  if (c > 0) {
    int n0 = tid << 9;
    int bucket_base = offs[n0] + bsum[n0 >> 8];
    base_[tid] = bucket_base + atomicAdd(&gcur[tid], c);
  }
  hist[tid] = 0;
  __syncthreads();
  for (int e = e0 + tid; e < e1; e += 256) {
    int d = dst[e];
    int b = d >> 9;
    int r = atomicAdd(&hist[b], 1);
    pairs[base_[b] + r] = (u32)src[e] | ((u32)(d & 511) << 17);
  }
}

// D4: blocks [0,NB): per-bucket CSR fill (cursors finalized locally);
//     blocks [NB,NB+saGrid): write finalized offs2.
__global__ __launch_bounds__(256) void fill2_k(
    const u32* __restrict__ pairs, const int* __restrict__ offs,
    const int* __restrict__ bsum, int* __restrict__ col,
    int* __restrict__ offs2, int N, int E, int NB) {
  const int tid = threadIdx.x;
  if ((int)blockIdx.x >= NB) {
    int i = (blockIdx.x - NB) * 256 + tid;
    if (i < N) offs2[i] = offs[i] + bsum[i >> 8];
    else if (i == N) offs2[N] = E;
    return;
  }
  __shared__ int cur[512];
  const int b = blockIdx.x;
  const int n0 = b << 9;
  const int n1 = min(N, n0 + 512);
  for (int i = tid; i < n1 - n0; i += 256)
    cur[i] = offs[n0 + i] + bsum[(n0 + i) >> 8];
  __syncthreads();
  const int e0 = offs[n0] + bsum[n0 >> 8];
  const int e1 = (n1 == N) ? E : offs[n1] + bsum[n1 >> 8];
  for (int e = e0 + tid; e < e1; e += 256) {
    u32 pr = pairs[e];
    int p = atomicAdd(&cur[pr >> 17], 1);
    col[p] = (int)(pr & 0x1FFFFu);
  }
}

// D5..D7: fused layer = SpMM gather + W2 GEMM + res/LN/ReLU + next GEMM.
// FINAL==0: write h; phase3 = y @ W1next -> msc_out (inv-scaled).
// FINAL==1: no h write; out-LN in-register; phase3 = z @ Wout -> d_out (fp32).
template <int FINAL>
__global__ __launch_bounds__(256) void layer_fused_k(
    const uint4* __restrict__ mscin, const int* __restrict__ offs,
    const int* __restrict__ col, const float* __restrict__ inv,
    const u16* __restrict__ pW2, const float* __restrict__ b2,
    u32* __restrict__ h, const float* __restrict__ g1,
    const float* __restrict__ lb1,
    const u16* __restrict__ pWn, const float* __restrict__ bn,
    void* __restrict__ outv, const float* __restrict__ og,
    const float* __restrict__ ob, int N) {
  __shared__ u16 xs[32][136];
  __shared__ float cs[16][132];
  const int tid = threadIdx.x;
  const int lane = tid & 63, wid = tid >> 6;
  const int row0 = blockIdx.x * 32;
  const int rgrp = lane >> 4, c = lane & 15;

  // ---- phase 1: gather (reduce-free, MLP 8) ----
#pragma unroll
  for (int p = 0; p < 2; ++p) {
    const int lrow = wid * 8 + p * 4 + rgrp;
    const int d = row0 + lrow;
    const int s0 = offs[d], s1 = offs[d + 1];
    const int last = s1 - 1;
    float2 a0 = {0.f, 0.f}, a1 = {0.f, 0.f}, a2 = {0.f, 0.f}, a3 = {0.f, 0.f};
    for (int k = s0; k < s1; k += 8) {
      int sv[8];
#pragma unroll
      for (int j = 0; j < 8; ++j) sv[j] = col[min(k + j, last)];
      uint4 rv[8];
#pragma unroll
      for (int j = 0; j < 8; ++j) rv[j] = mscin[(size_t)sv[j] * 16 + c];
#pragma unroll
      for (int j = 0; j < 8; ++j) {
        float m = (k + j < s1) ? 1.f : 0.f;
        a0.x = fmaf(m, bflo(rv[j].x), a0.x); a0.y = fmaf(m, bfhi(rv[j].x), a0.y);
        a1.x = fmaf(m, bflo(rv[j].y), a1.x); a1.y = fmaf(m, bfhi(rv[j].y), a1.y);
        a2.x = fmaf(m, bflo(rv[j].z), a2.x); a2.y = fmaf(m, bfhi(rv[j].z), a2.y);
        a3.x = fmaf(m, bflo(rv[j].w), a3.x); a3.y = fmaf(m, bfhi(rv[j].w), a3.y);
      }
    }
    uint4 r = mscin[(size_t)d * 16 + c];   // self loop
    float iv = inv[d];
    uint4 o;
    o.x = pack2((a0.x + bflo(r.x)) * iv, (a0.y + bfhi(r.x)) * iv);
    o.y = pack2((a1.x + bflo(r.y)) * iv, (a1.y + bfhi(r.y)) * iv);
    o.z = pack2((a2.x + bflo(r.z)) * iv, (a2.y + bfhi(r.z)) * iv);
    o.w = pack2((a3.x + bflo(r.w)) * iv, (a3.y + bfhi(r.w)) * iv);
    *(uint4*)&xs[lrow][c * 8] = o;
  }
  __syncthreads();

  // ---- phase 2: W2 MFMA ----
  const int m0  = (wid >> 1) << 4;
  const int ntb = (wid & 1) << 2;
  f32x4 acc[4];
#pragma unroll
  for (int t = 0; t < 4; ++t) acc[t] = (f32x4){0.f, 0.f, 0.f, 0.f};
  MFMA128_FROM_XS(acc, (const bf16x8*)pW2);

  // ---- epilogue: bias + residual + LN + ReLU (y -> h and/or xs) ----
  const int cb = lane & 15;
  const int rg = (lane >> 4) << 2;
  float2 gg = *(const float2*)&g1[lane * 2];
  float2 bb = *(const float2*)&lb1[lane * 2];
  float2 ogg, obb;
  if constexpr (FINAL) {
    ogg = *(const float2*)&og[lane * 2];
    obb = *(const float2*)&ob[lane * 2];
  }
#pragma unroll
  for (int hh = 0; hh < 2; ++hh) {
    __syncthreads();
    if ((m0 >> 4) == hh) {
#pragma unroll
      for (int t = 0; t < 4; ++t) {
        int colm = (ntb + t) * 16 + cb;
        float bv = b2[colm];
#pragma unroll
        for (int r = 0; r < 4; ++r) cs[rg + r][colm] = acc[t][r] + bv;
      }
    }
    __syncthreads();
    for (int rr = 0; rr < 4; ++rr) {
      int lr = wid * 4 + rr;
      int r = hh * 16 + lr;
      int gr = row0 + r;
      float2 t2 = *(const float2*)&cs[lr][lane * 2];
      u32 hv = h[(size_t)gr * 64 + lane];
      float tx = t2.x + bflo(hv), ty = t2.y + bfhi(hv);
      float mean = wred(tx + ty) * (1.f / 128.f);
      float dx = tx - mean, dy = ty - mean;
      float var = wred(dx * dx + dy * dy) * (1.f / 128.f);
      float rstd = rsqrtf(var + 1e-5f);
      float y0 = fmaxf(dx * rstd * gg.x + bb.x, 0.f);
      float y1 = fmaxf(dy * rstd * gg.y + bb.y, 0.f);
      if constexpr (!FINAL) {
        u32 pk = pack2(y0, y1);
        h[(size_t)gr * 64 + lane] = pk;
        *(u32*)&xs[r][lane * 2] = pk;
      } else {
        float m2 = wred(y0 + y1) * (1.f / 128.f);
        float dx2 = y0 - m2, dy2 = y1 - m2;
        float v2 = wred(dx2 * dx2 + dy2 * dy2) * (1.f / 128.f);
        float rs2 = rsqrtf(v2 + 1e-5f);
        *(u32*)&xs[r][lane * 2] =
            pack2(dx2 * rs2 * ogg.x + obb.x, dy2 * rs2 * ogg.y + obb.y);
      }
    }
  }
  __syncthreads();

  // ---- phase 3 ----
  if constexpr (!FINAL) {
    f32x4 acc2[4];
#pragma unroll
    for (int t = 0; t < 4; ++t) acc2[t] = (f32x4){0.f, 0.f, 0.f, 0.f};
    MFMA128_FROM_XS(acc2, (const bf16x8*)pWn);
    u16* Y = (u16*)outv;
    float iv4[4];
#pragma unroll
    for (int r = 0; r < 4; ++r) iv4[r] = inv[row0 + m0 + rg + r];
#pragma unroll
    for (int t = 0; t < 4; ++t) {
      int colm = (ntb + t) * 16 + cb;
      float bv = bn[colm];
#pragma unroll
      for (int r = 0; r < 4; ++r) {
        int gr = row0 + m0 + rg + r;
        Y[(size_t)gr * 128 + colm] = f2bf((acc2[t][r] + bv) * iv4[r]);
      }
    }
  } else {
    const int m0b = (wid & 1) << 4;
    const int ntbb = (wid >> 1) << 1;
    const int arb = m0b + (lane & 15);
    const int akb = (lane >> 4) << 2;
    f32x4 acc2[2];
#pragma unroll
    for (int t = 0; t < 2; ++t) acc2[t] = (f32x4){0.f, 0.f, 0.f, 0.f};
    const bf16x8* Bp = (const bf16x8*)pWn;
#pragma unroll
    for (int kc = 0; kc < 4; ++kc) {
      u16x4 lo = *(const u16x4*)&xs[arb][kc * 32 + akb];
      u16x4 hi = *(const u16x4*)&xs[arb][kc * 32 + akb + 16];
      u16x8 av;
#pragma unroll
      for (int j = 0; j < 4; ++j) { av[j] = lo[j]; av[j + 4] = hi[j]; }
      bf16x8 a = __builtin_bit_cast(bf16x8, av);
#pragma unroll
      for (int t = 0; t < 2; ++t) {
        bf16x8 b = Bp[(kc * 4 + ntbb + t) * 64 + lane];
        acc2[t] = __builtin_amdgcn_mfma_f32_16x16x32_bf16(a, b, acc2[t], 0, 0, 0);
      }
    }
    float* Y = (float*)outv;
#pragma unroll
    for (int t = 0; t < 2; ++t) {
      int colo = (ntbb + t) * 16 + cb;
      float bv = bn[colo];
#pragma unroll
      for (int r = 0; r < 4; ++r) {
        int gr = row0 + m0b + rg + r;
        Y[(size_t)gr * 64 + colo] = acc2[t][r] + bv;
      }
    }
  }
}

// ---------------------------------------------------------------------------
extern "C" void kernel_launch(void* const* d_in, const int* in_sizes, int n_in,
                              void* d_out, int out_size, void* d_ws, size_t ws_size,
                              hipStream_t stream) {
  (void)n_in; (void)out_size; (void)ws_size;
  const float* x      = (const float*)d_in[0];
  const int*   eidx   = (const int*)d_in[1];
  const float* degree = (const float*)d_in[2];
  const float* Win    = (const float*)d_in[3];
  const float* b_in   = (const float*)d_in[4];
  const float* W1     = (const float*)d_in[5];
  const float* b1     = (const float*)d_in[6];
  const float* W2     = (const float*)d_in[7];
  const float* b2     = (const float*)d_in[8];
  const float* ln_g   = (const float*)d_in[9];
  const float* ln_b   = (const float*)d_in[10];
  const float* out_g  = (const float*)d_in[11];
  const float* out_b  = (const float*)d_in[12];
  const float* Wout   = (const float*)d_in[13];
  const float* b_out  = (const float*)d_in[14];

  const int N = in_sizes[0] / 128;
  const int E = in_sizes[1] / 2;
  const int* esrc = eidx;
  const int* edst = eidx + E;

  char* p = (char*)d_ws;
  auto alloc = [&](size_t bytes) {
    char* q = p;
    p += (bytes + 255) & ~(size_t)255;
    return q;
  };
  float* inv    = (float*)alloc((size_t)N * 4);
  int*   offs   = (int*)alloc(((size_t)N + 1) * 4);
  int*   offs2  = (int*)alloc(((size_t)N + 1) * 4);
  int*   gcur   = (int*)alloc(256 * 4);
  int*   bsum   = (int*)alloc(1024 * 4);
  int*   col    = (int*)alloc((size_t)E * 4);
  u32*   pairs  = (u32*)alloc((size_t)E * 4);
  u32*   h      = (u32*)alloc((size_t)N * 128 * 2);     // bf16 residual
  u32*   mscA   = (u32*)alloc((size_t)N * 128 * 2);     // bf16 ping
  u32*   mscB   = (u32*)alloc((size_t)N * 128 * 2);     // bf16 pong
  u16*   pWin   = (u16*)alloc(4 * 8 * 64 * 8 * 2);
  u16*   pWout  = (u16*)alloc(4 * 4 * 64 * 8 * 2);
  u16*   pW1    = (u16*)alloc(3 * 4 * 8 * 64 * 8 * 2);
  u16*   pW2    = (u16*)alloc(3 * 4 * 8 * 64 * 8 * 2);

  const int nb = (N + 255) / 256;              // scan blocks (<=512 req'd)
  const int NB = (N + 511) / 512;              // dst buckets
  const int gemmGrid = (N + 31) / 32;          // 3125
  const int saGrid = (N + 256) / 256;

  // D1: degree scan + inv + weight packing
  d1_scan_pack_k<<<nb + 60, 256, 0, stream>>>(
      degree, offs, bsum, inv, N, nb,
      Win, W1, W2, Wout, pWin, pW1, pW2, pWout);
  // D2: x@Win+ReLU -> h, y@W1(l0) -> mscA  (+ bsum scan, gcur init)
  in_scale_k<<<gemmGrid + 1, 256, 0, stream>>>(
      x, pWin, b_in, pW1, b1, inv, h, (u16*)mscA, N, bsum, nb, gcur);
  // D3: edge bucket-scatter (derives bucket bases from offs+bsum)
  scatter_k<<<(E + 8191) / 8192, 256, 0, stream>>>(
      esrc, edst, gcur, pairs, offs, bsum, E);
  // D4: CSR fill + offs2 finalize
  fill2_k<<<NB + saGrid, 256, 0, stream>>>(
      pairs, offs, bsum, col, offs2, N, E, NB);

  // D5: layer 0  (mscA -> h, mscB)
  layer_fused_k<0><<<gemmGrid, 256, 0, stream>>>(
      (const uint4*)mscA, offs2, col, inv, pW2, b2, h, ln_g, ln_b,
      pW1 + 16384, b1 + 128, mscB, nullptr, nullptr, N);
  // D6: layer 1  (mscB -> h, mscA)
  layer_fused_k<0><<<gemmGrid, 256, 0, stream>>>(
      (const uint4*)mscB, offs2, col, inv, pW2 + 16384, b2 + 128, h,
      ln_g + 128, ln_b + 128, pW1 + 32768, b1 + 256, mscA, nullptr, nullptr, N);
  // D7: layer 2 + out-LN + Wout  (mscA -> d_out)
  layer_fused_k<1><<<gemmGrid, 256, 0, stream>>>(
      (const uint4*)mscA, offs2, col, inv, pW2 + 32768, b2 + 256, h,
      ln_g + 256, ln_b + 256, pWout, b_out, d_out, out_g, out_b, N);
}